// Round 8
// baseline (901.073 us; speedup 1.0000x reference)
//
#include <hip/hip_runtime.h>
#include <math.h>

// (B, T, D, H, L) = (8, 512, 128, 128, 2). All fp32 I/O.
// CHUNKED SCAN REFORMULATION: T split into NC=16 chunks of CS=32.
//   P_s[i] = prod_{u<=s} f_u[i] (per chunk), G[i][s] = i_s v_s / P_s[i]
//   h~_s[i] = P_{s-1}[i] ( (C_b q_s)[i] + sum_{s'<s} A[s][s'] G[i][s'] )
//   C_end[i,:] = P_31[i] ( C_b[i,:] + sum_s' G[i][s'] k_s'[:] )
//   A[s][s'] = k_s' . q_s  (row-independent, precomputed+masked)
//   denom precomputed from exact sequential n (elementwise recurrence).
#define BB 8
#define TT 512
#define DD 128
#define HH 128
#define CS 32
#define NC 16
#define BT_ (BB * TT)
static const size_t BTH = (size_t)BT_ * HH;  // 524288

// ws planes (floats): q 0 | k BTH | i->Pm1 2BTH | f 3BTH | v->G 4BTH | o 5BTH
//                     hbuf 6BTH | Abuf 7BTH (131072) | invd +131072 (4096)
// Wt (12x128x128, plane order q,k,i,f,v,o per layer) in d_out's first 196608
// floats; consumed by both proj dispatches before the final seqk overwrites
// d_out (stream-ordered, safe). Total ws use = 15.2 MB.

struct WArgs { const float* W[6]; };
struct BArgs { const float* b[6]; };

template <int CTRL>
__device__ __forceinline__ float dpp_add(float x) {
  int y = __builtin_amdgcn_update_dpp(0, __builtin_bit_cast(int, x), CTRL,
                                      0xF, 0xF, true);
  return x + __builtin_bit_cast(float, y);
}
// full 64-lane sum; valid at lane 63
__device__ __forceinline__ float red64(float x) {
  x = dpp_add<0x111>(x);  // row_shr:1
  x = dpp_add<0x112>(x);  // row_shr:2
  x = dpp_add<0x114>(x);  // row_shr:4
  x = dpp_add<0x118>(x);  // row_shr:8
  x = dpp_add<0x142>(x);  // row_bcast:15
  x = dpp_add<0x143>(x);  // row_bcast:31
  return x;
}

// ---------------------------------------------------------------------------
// Transpose weight slabs into plane order: Wt[l*6+p][d][h] = W_p[l][h][d].
// ---------------------------------------------------------------------------
__global__ __launch_bounds__(256)
void transpose_w(WArgs w, float* __restrict__ Wt) {
  __shared__ float t[32][33];
  const int l = blockIdx.y / 6, p = blockIdx.y % 6;
  const float* src = w.W[p] + (size_t)l * HH * DD;
  float* dst = Wt + (size_t)blockIdx.y * HH * DD;
  const int ty0 = (blockIdx.x >> 2) * 32, tx0 = (blockIdx.x & 3) * 32;
  const int tx = threadIdx.x & 31, ty = threadIdx.x >> 5;
#pragma unroll
  for (int j = 0; j < 32; j += 8)
    t[ty + j][tx] = src[(size_t)(ty0 + ty + j) * DD + tx0 + tx];
  __syncthreads();
#pragma unroll
  for (int j = 0; j < 32; j += 8)
    dst[(size_t)(tx0 + ty + j) * HH + ty0 + tx] = t[tx][ty + j];
}

// ---------------------------------------------------------------------------
// Projection: plane[p][row][h] = act_p( X[row][:] . Wt[p][:][h] + b_p[h] )
// plane/act map: 0=q 1=k(*1/sqrt H) 2=i(exp) 3=f(sigm) 4=v 5=o(sigm)
// grid (32, 6), block 256 (16 rg x 16 cg). Thread = 8 rows x 8 cols.
// X tile in LDS, skewed by 4*rg so x4 reads are bank-conflict-free.
// W streamed from global coalesced (row-tile reuse 128 -> ~12MB L2 traffic).
// ---------------------------------------------------------------------------
__global__ __launch_bounds__(256)
void proj_kernel(const float* __restrict__ X, const float* __restrict__ Wtl,
                 BArgs args, float* __restrict__ act) {
  __shared__ float Xs[128 * 132];
  const int p = blockIdx.y;
  const int row0 = blockIdx.x * 128;
  const int tid = threadIdx.x;
  {
    const float4* xg = (const float4*)(X + (size_t)row0 * DD);
#pragma unroll
    for (int m = 0; m < 16; ++m) {
      const int v = tid + 256 * m;  // 4096 float4s: 128 rows x 32
      const int row = v >> 5, d0 = (v & 31) * 4;
      const float4 val = xg[v];
      *(float4*)&Xs[row * 132 + ((d0 + 4 * (row >> 3)) & 127)] = val;
    }
  }
  __syncthreads();

  const int cg = tid & 15, rg = tid >> 4;
  const int c0 = cg * 8;
  const float* wp = Wtl + (size_t)p * HH * DD + c0;

  float acc[8][8];
#pragma unroll
  for (int j = 0; j < 8; ++j)
#pragma unroll
    for (int c = 0; c < 8; ++c) acc[j][c] = 0.f;

#pragma unroll 2
  for (int dq = 0; dq < 32; ++dq) {
    const int d0 = dq * 4;
    float w[4][8];
#pragma unroll
    for (int i = 0; i < 4; ++i) {
      const float4 wa = *(const float4*)(wp + (size_t)(d0 + i) * HH);
      const float4 wb = *(const float4*)(wp + (size_t)(d0 + i) * HH + 4);
      w[i][0] = wa.x; w[i][1] = wa.y; w[i][2] = wa.z; w[i][3] = wa.w;
      w[i][4] = wb.x; w[i][5] = wb.y; w[i][6] = wb.z; w[i][7] = wb.w;
    }
    float xf[8][4];
#pragma unroll
    for (int j = 0; j < 8; ++j) {
      const float4 xv =
          *(const float4*)&Xs[(rg * 8 + j) * 132 + ((d0 + 4 * rg) & 127)];
      xf[j][0] = xv.x; xf[j][1] = xv.y; xf[j][2] = xv.z; xf[j][3] = xv.w;
    }
#pragma unroll
    for (int i = 0; i < 4; ++i)
#pragma unroll
      for (int j = 0; j < 8; ++j)
#pragma unroll
        for (int c = 0; c < 8; ++c)
          acc[j][c] = fmaf(xf[j][i], w[i][c], acc[j][c]);
  }

  const float4 b0 = *(const float4*)(args.b[p] + c0);
  const float4 b1 = *(const float4*)(args.b[p] + c0 + 4);
  const float bias[8] = {b0.x, b0.y, b0.z, b0.w, b1.x, b1.y, b1.z, b1.w};
#pragma unroll
  for (int j = 0; j < 8; ++j) {
    float v[8];
#pragma unroll
    for (int c = 0; c < 8; ++c) {
      float a = acc[j][c] + bias[c];
      if (p == 1)      a *= 0.088388347648318447f;
      else if (p == 2) a = __expf(a);
      else if (p == 3 || p == 5) a = 1.0f / (1.0f + __expf(-a));
      v[c] = a;
    }
    float* dst = act + (size_t)p * BTH + (size_t)(row0 + rg * 8 + j) * HH + c0;
    *(float4*)dst = make_float4(v[0], v[1], v[2], v[3]);
    *(float4*)(dst + 4) = make_float4(v[4], v[5], v[6], v[7]);
  }
}

// ---------------------------------------------------------------------------
// nker: exact sequential n recurrence (elementwise) fused with denom.
// grid 8 (b), block 64. Lane owns n at cols {2l, 2l+1}.
// invd[b][t] = 1 / max(|n_{t-1} . q_t|, 1)   (n pre-update = n_{t-1})
// ---------------------------------------------------------------------------
__global__ __launch_bounds__(64)
void nker(const float* __restrict__ act, float* __restrict__ invd) {
  const int b = blockIdx.x;
  const int lane = threadIdx.x;
  const float* qp = act;
  const float* kp = act + BTH;
  const float* ip = act + 2 * BTH;
  const float* fp = act + 3 * BTH;
  float n0 = 0.f, n1 = 0.f;
#pragma unroll 2
  for (int t = 0; t < TT; ++t) {
    const size_t base = ((size_t)b * TT + t) * HH + 2 * lane;
    const float2 qv = *(const float2*)(qp + base);
    const float2 kv = *(const float2*)(kp + base);
    const float2 iv = *(const float2*)(ip + base);
    const float2 fv = *(const float2*)(fp + base);
    float dp = red64(fmaf(n0, qv.x, n1 * qv.y));
    if (lane == 63) invd[b * TT + t] = 1.0f / fmaxf(fabsf(dp), 1.0f);
    n0 = fmaf(fv.x, n0, iv.x * kv.x);
    n1 = fmaf(fv.y, n1, iv.y * kv.y);
  }
}

// ---------------------------------------------------------------------------
// gker: per (b, chunk, i): cumprod P, write Pm1 over i-plane, G over v-plane.
// grid 128 ((b<<4)|c), block 128 (i). Each slot read+written by its own
// thread in the same iteration -> safe in-place.
// ---------------------------------------------------------------------------
__global__ __launch_bounds__(128)
void gker(float* __restrict__ act) {
  const int b = blockIdx.x >> 4, c = blockIdx.x & 15;
  const int i = threadIdx.x;
  float* iP = act + 2 * BTH;
  float* fP = act + 3 * BTH;
  float* vG = act + 4 * BTH;
  float P = 1.f;
#pragma unroll 1
  for (int s = 0; s < CS; ++s) {
    const size_t base = ((size_t)b * TT + CS * c + s) * HH + i;
    const float fv = fP[base], iv = iP[base], vv = vG[base];
    iP[base] = P;            // Pm1 (P_{s-1})
    P *= fv;
    vG[base] = iv * vv / P;  // G
  }
}

// ---------------------------------------------------------------------------
// aker: A[b][c][s][s'] = (s' < s) ? q_s . k_s' : 0.   grid 128, block 256.
// Thread = 2x2 tile of the 32x32 output.
// ---------------------------------------------------------------------------
#define PADQ 132
__global__ __launch_bounds__(256)
void aker(const float* __restrict__ act, float* __restrict__ Abuf) {
  __shared__ float Qc[CS * PADQ], Kc[CS * PADQ];
  const int b = blockIdx.x >> 4, c = blockIdx.x & 15;
  const int tid = threadIdx.x;
  const size_t cb = ((size_t)b * TT + CS * c) * HH;
  {
    const float4* qg = (const float4*)(act + cb);
    const float4* kg = (const float4*)(act + BTH + cb);
#pragma unroll
    for (int m = 0; m < 4; ++m) {
      const int v = tid + 256 * m;  // 1024 f4
      const int s = v >> 5, d0 = (v & 31) * 4;
      *(float4*)&Qc[s * PADQ + d0] = qg[v];
      *(float4*)&Kc[s * PADQ + d0] = kg[v];
    }
  }
  __syncthreads();
  const int s2 = tid >> 4, sp2 = tid & 15;
  float a00 = 0, a01 = 0, a10 = 0, a11 = 0;
#pragma unroll 2
  for (int dq = 0; dq < 32; ++dq) {
    const int d0 = dq * 4;
    const float4 qa = *(const float4*)&Qc[(2 * s2) * PADQ + d0];
    const float4 qb = *(const float4*)&Qc[(2 * s2 + 1) * PADQ + d0];
    const float4 ka = *(const float4*)&Kc[(2 * sp2) * PADQ + d0];
    const float4 kb = *(const float4*)&Kc[(2 * sp2 + 1) * PADQ + d0];
    a00 += qa.x*ka.x + qa.y*ka.y + qa.z*ka.z + qa.w*ka.w;
    a01 += qa.x*kb.x + qa.y*kb.y + qa.z*kb.z + qa.w*kb.w;
    a10 += qb.x*ka.x + qb.y*ka.y + qb.z*ka.z + qb.w*ka.w;
    a11 += qb.x*kb.x + qb.y*kb.y + qb.z*kb.z + qb.w*kb.w;
  }
  float* dst = Abuf + (size_t)(b * NC + c) * 1024;
  const int sa = 2 * s2, sb = 2 * s2 + 1, ta = 2 * sp2, tb = 2 * sp2 + 1;
  dst[sa * 32 + ta] = (ta < sa) ? a00 : 0.f;
  dst[sa * 32 + tb] = (tb < sa) ? a01 : 0.f;
  dst[sb * 32 + ta] = (ta < sb) ? a10 : 0.f;
  dst[sb * 32 + tb] = (tb < sb) ? a11 : 0.f;
}

// ---------------------------------------------------------------------------
// seqk: 16 sequential chunk iterations. grid 64 (b = &7, slice = >>3 of 16 C
// rows), block 256 = 4 waves (wave w -> rows 4w..4w+3 of slice), lane owns
// C cols {2l, 2l+1} -> C[4][2] regs. Double-buffered LDS staging.
// s-loop: (C_b q_s) + masked A.G merged into one 64-lane DPP reduce/row.
// ---------------------------------------------------------------------------
#define Q_OFF 0
#define K_OFF 4224
#define A_OFF 8448
#define G_OFF 9472
#define P_OFF 9984
#define O_OFF 10496
#define V_OFF 11008
#define F_OFF 11040
#define BUFS  11056
#define HST_OFF (2 * BUFS)

struct SR { float4 q[4], k[4], a, x1, x2, x3; };

__global__ __launch_bounds__(256, 1)
void seqk(const float* __restrict__ act, const float* __restrict__ Abuf,
          const float* __restrict__ invd, float* __restrict__ hout) {
  __shared__ float smem[2 * BUFS + CS * 16];
  const int tid = threadIdx.x;
  const int b = blockIdx.x & 7, sl = blockIdx.x >> 3;
  const int lane = tid & 63, w = tid >> 6;
  const float* qp = act;
  const float* kp = act + BTH;
  const float* Pm1p = act + 2 * BTH;   // was i-plane
  const float* fp = act + 3 * BTH;
  const float* Gp = act + 4 * BTH;     // was v-plane
  const float* op = act + 5 * BTH;

  float C[4][2];
#pragma unroll
  for (int j = 0; j < 4; ++j) { C[j][0] = 0.f; C[j][1] = 0.f; }

  auto stage_load = [&](int c, SR& sr) {
    const size_t cb = ((size_t)b * TT + CS * c) * HH;
    const float4* qg = (const float4*)(qp + cb);
    const float4* kg = (const float4*)(kp + cb);
#pragma unroll
    for (int m = 0; m < 4; ++m) {
      sr.q[m] = qg[tid + 256 * m];
      sr.k[m] = kg[tid + 256 * m];
    }
    sr.a = ((const float4*)(Abuf + (size_t)(b * NC + c) * 1024))[tid];
    const int t1 = tid & 127;
    const int s = t1 >> 2, j0 = (t1 & 3) * 4;
    const float* p1 = (tid < 128) ? Gp : Pm1p;
    sr.x1 = *(const float4*)(p1 + cb + (size_t)s * HH + sl * 16 + j0);
    sr.x2 = *(const float4*)(op + cb + (size_t)s * HH + sl * 16 + j0);
    if (tid < 8)
      sr.x3 = *(const float4*)(invd + b * TT + CS * c + tid * 4);
    else if (tid < 12)
      sr.x3 = *(const float4*)(fp + cb + (size_t)31 * HH + sl * 16 +
                               (tid - 8) * 4);
  };
  auto stage_store = [&](int d, const SR& sr) {
    float* B = smem + d * BUFS;
#pragma unroll
    for (int m = 0; m < 4; ++m) {
      const int v = tid + 256 * m;
      const int s = v >> 5, d0 = (v & 31) * 4;
      *(float4*)&B[Q_OFF + s * PADQ + d0] = sr.q[m];
      *(float4*)&B[K_OFF + s * PADQ + d0] = sr.k[m];
    }
    { const int s = tid >> 3, o = (tid & 7) * 4;
      *(float4*)&B[A_OFF + s * 32 + o] = sr.a; }
    { const int t1 = tid & 127;
      const int s = t1 >> 2, j0 = (t1 & 3) * 4;
      if (tid < 128) {
        *(float4*)&B[G_OFF + s * 16 + j0] = sr.x1;
        *(float4*)&B[O_OFF + s * 16 + j0] = sr.x2;
      } else {
        *(float4*)&B[P_OFF + s * 16 + j0] = sr.x1;
      } }
    if (tid < 8) *(float4*)&B[V_OFF + tid * 4] = sr.x3;
    else if (tid < 12) *(float4*)&B[F_OFF + (tid - 8) * 4] = sr.x3;
  };

  SR sr;
  stage_load(0, sr);
  stage_store(0, sr);
  __syncthreads();

#pragma unroll 1
  for (int c = 0; c < NC; ++c) {
    if (c + 1 < NC) stage_load(c + 1, sr);   // global loads overlap compute
    const float* B = smem + (c & 1) * BUFS;
    const float4 Greg = *(const float4*)&B[G_OFF + (lane & 31) * 16 + 4 * w];

    // ---- h pass: uses boundary C only ----
#pragma unroll 2
    for (int s = 0; s < CS; ++s) {
      const float2 qv = *(const float2*)&B[Q_OFF + s * PADQ + 2 * lane];
      float av = B[A_OFF + s * 32 + (lane & 31)];
      av = (lane < 32) ? av : 0.f;
      float r0 = fmaf(C[0][0], qv.x, fmaf(C[0][1], qv.y, av * Greg.x));
      float r1 = fmaf(C[1][0], qv.x, fmaf(C[1][1], qv.y, av * Greg.y));
      float r2 = fmaf(C[2][0], qv.x, fmaf(C[2][1], qv.y, av * Greg.z));
      float r3 = fmaf(C[3][0], qv.x, fmaf(C[3][1], qv.y, av * Greg.w));
      r0 = red64(r0); r1 = red64(r1); r2 = red64(r2); r3 = red64(r3);
      if (lane == 63)
        *(float4*)&smem[HST_OFF + s * 16 + 4 * w] = make_float4(r0, r1, r2, r3);
    }
    __syncthreads();

    // ---- state update: C = P31 * (C + sum_s' G[.][s'] k_s') ----
#pragma unroll 4
    for (int sp = 0; sp < CS; ++sp) {
      const float2 kv = *(const float2*)&B[K_OFF + sp * PADQ + 2 * lane];
      const float4 g4 = *(const float4*)&B[G_OFF + sp * 16 + 4 * w];
      C[0][0] = fmaf(g4.x, kv.x, C[0][0]); C[0][1] = fmaf(g4.x, kv.y, C[0][1]);
      C[1][0] = fmaf(g4.y, kv.x, C[1][0]); C[1][1] = fmaf(g4.y, kv.y, C[1][1]);
      C[2][0] = fmaf(g4.z, kv.x, C[2][0]); C[2][1] = fmaf(g4.z, kv.y, C[2][1]);
      C[3][0] = fmaf(g4.w, kv.x, C[3][0]); C[3][1] = fmaf(g4.w, kv.y, C[3][1]);
    }
    { const float4 pm = *(const float4*)&B[P_OFF + 31 * 16 + 4 * w];
      const float4 f31 = *(const float4*)&B[F_OFF + 4 * w];
      const float p31[4] = {pm.x * f31.x, pm.y * f31.y, pm.z * f31.z,
                            pm.w * f31.w};
#pragma unroll
      for (int j = 0; j < 4; ++j) { C[j][0] *= p31[j]; C[j][1] *= p31[j]; } }

    // ---- epilogue: h = o * invd * Pm1 * (inter+intra) ----
#pragma unroll
    for (int e = 0; e < 2; ++e) {
      const int v = tid + 256 * e;  // 512 = 32 s x 16 rows
      const int s = v >> 4, j = v & 15;
      const float hv =
          smem[HST_OFF + v] * B[P_OFF + v] * B[O_OFF + v] * B[V_OFF + s];
      hout[((size_t)b * TT + CS * c + s) * HH + sl * 16 + j] = hv;
    }

    if (c + 1 < NC) stage_store((c + 1) & 1, sr);
    __syncthreads();
  }
}

// ---------------------------------------------------------------------------
extern "C" void kernel_launch(void* const* d_in, const int* in_sizes, int n_in,
                              void* d_out, int out_size, void* d_ws,
                              size_t ws_size, hipStream_t stream) {
  (void)in_sizes; (void)n_in; (void)out_size; (void)ws_size;
  const float* x = (const float*)d_in[0];
  float* act = (float*)d_ws;
  float* hbuf = act + 6 * BTH;
  float* Abuf = act + 7 * BTH;
  float* invd = Abuf + (size_t)BB * NC * 1024;
  float* Wt = (float*)d_out;  // 196608 floats, consumed before final seqk

  // plane order q,k,i,f,v,o -> d_in W indices {1,2,4,5,3,6}, b {7,8,10,11,9,12}
  const int wi[6] = {1, 2, 4, 5, 3, 6};
  const int bi[6] = {7, 8, 10, 11, 9, 12};
  WArgs wa;
  for (int j = 0; j < 6; ++j) wa.W[j] = (const float*)d_in[wi[j]];
  transpose_w<<<dim3(16, 12), 256, 0, stream>>>(wa, Wt);

  for (int l = 0; l < 2; ++l) {
    BArgs ba;
    for (int j = 0; j < 6; ++j)
      ba.b[j] = (const float*)d_in[bi[j]] + (size_t)l * HH;
    const float* wtl = Wt + (size_t)l * 6 * HH * DD;
    const float* xin = (l == 0) ? x : hbuf;
    float* hdst = (l == 0) ? hbuf : (float*)d_out;
    proj_kernel<<<dim3(32, 6), 256, 0, stream>>>(xin, wtl, ba, act);
    nker<<<8, 64, 0, stream>>>(act, invd);
    gker<<<128, 128, 0, stream>>>(act);
    aker<<<128, 256, 0, stream>>>(act, Abuf);
    seqk<<<64, 256, 0, stream>>>(act, Abuf, invd, hdst);
  }
}

// Round 9
// 458.737 us; speedup vs baseline: 1.9642x; 1.9642x over previous
//
#include <hip/hip_runtime.h>
#include <math.h>

// (B, T, D, H, L) = (8, 512, 128, 128, 2). All fp32 I/O.
// CHUNKED SCAN: T split into NC=16 chunks of CS=32.
//   P_s[i] = prod_{u<=s} f_u[i] (per chunk), G[i][s] = i_s v_s / P_s[i]
//   h~_s[i] = P_{s-1}[i] ( (C_b q_s)[i] + sum_{s'<s} A[s][s'] G[i][s'] )
//   C_end[i,:] = P_31[i] ( C_b[i,:] + sum_s' G[i][s'] k_s'[:] )
//   A[s][s'] = k_s' . q_s  (row-independent, precomputed+masked)
// n-recurrence chunk-factorized the same way (sker/n2ker/dker): exact
// boundary vectors then 32-step intra-chunk recurrence for denominators.
#define BB 8
#define TT 512
#define DD 128
#define HH 128
#define CS 32
#define NC 16
#define BT_ (BB * TT)
static const size_t BTH = (size_t)BT_ * HH;  // 524288

// ws planes (floats): q 0 | k BTH | i->Pm1 2BTH | f 3BTH | v->G 4BTH | o 5BTH
//   hbuf 6BTH | Abuf 7BTH (131072) | invd (4096) | P31s (16384) | Sns (16384)
//   nbs (16384).  Total ~15.4 MB.
// Wt (12x128x128, plane order q,k,i,f,v,o per layer) in d_out's first 196608
// floats; consumed before the final seqk overwrites d_out.

struct WArgs { const float* W[6]; };
struct BArgs { const float* b[6]; };

template <int CTRL>
__device__ __forceinline__ float dpp_add(float x) {
  int y = __builtin_amdgcn_update_dpp(0, __builtin_bit_cast(int, x), CTRL,
                                      0xF, 0xF, true);
  return x + __builtin_bit_cast(float, y);
}
// full 64-lane sum; valid at lane 63
__device__ __forceinline__ float red64(float x) {
  x = dpp_add<0x111>(x);
  x = dpp_add<0x112>(x);
  x = dpp_add<0x114>(x);
  x = dpp_add<0x118>(x);
  x = dpp_add<0x142>(x);
  x = dpp_add<0x143>(x);
  return x;
}

// ---------------------------------------------------------------------------
__global__ __launch_bounds__(256)
void transpose_w(WArgs w, float* __restrict__ Wt) {
  __shared__ float t[32][33];
  const int l = blockIdx.y / 6, p = blockIdx.y % 6;
  const float* src = w.W[p] + (size_t)l * HH * DD;
  float* dst = Wt + (size_t)blockIdx.y * HH * DD;
  const int ty0 = (blockIdx.x >> 2) * 32, tx0 = (blockIdx.x & 3) * 32;
  const int tx = threadIdx.x & 31, ty = threadIdx.x >> 5;
#pragma unroll
  for (int j = 0; j < 32; j += 8)
    t[ty + j][tx] = src[(size_t)(ty0 + ty + j) * DD + tx0 + tx];
  __syncthreads();
#pragma unroll
  for (int j = 0; j < 32; j += 8)
    dst[(size_t)(tx0 + ty + j) * HH + ty0 + tx] = t[tx][ty + j];
}

// ---------------------------------------------------------------------------
// Projection: plane[p][row][h] = act_p( X[row][:] . Wt[p][:][h] + b_p[h] )
// plane map: 0=q 1=k(*1/sqrt H) 2=i(exp) 3=f(sigm) 4=v 5=o(sigm)
// ---------------------------------------------------------------------------
__global__ __launch_bounds__(256)
void proj_kernel(const float* __restrict__ X, const float* __restrict__ Wtl,
                 BArgs args, float* __restrict__ act) {
  __shared__ float Xs[128 * 132];
  const int p = blockIdx.y;
  const int row0 = blockIdx.x * 128;
  const int tid = threadIdx.x;
  {
    const float4* xg = (const float4*)(X + (size_t)row0 * DD);
#pragma unroll
    for (int m = 0; m < 16; ++m) {
      const int v = tid + 256 * m;
      const int row = v >> 5, d0 = (v & 31) * 4;
      const float4 val = xg[v];
      *(float4*)&Xs[row * 132 + ((d0 + 4 * (row >> 3)) & 127)] = val;
    }
  }
  __syncthreads();

  const int cg = tid & 15, rg = tid >> 4;
  const int c0 = cg * 8;
  const float* wp = Wtl + (size_t)p * HH * DD + c0;

  float acc[8][8];
#pragma unroll
  for (int j = 0; j < 8; ++j)
#pragma unroll
    for (int c = 0; c < 8; ++c) acc[j][c] = 0.f;

#pragma unroll 2
  for (int dq = 0; dq < 32; ++dq) {
    const int d0 = dq * 4;
    float w[4][8];
#pragma unroll
    for (int i = 0; i < 4; ++i) {
      const float4 wa = *(const float4*)(wp + (size_t)(d0 + i) * HH);
      const float4 wb = *(const float4*)(wp + (size_t)(d0 + i) * HH + 4);
      w[i][0] = wa.x; w[i][1] = wa.y; w[i][2] = wa.z; w[i][3] = wa.w;
      w[i][4] = wb.x; w[i][5] = wb.y; w[i][6] = wb.z; w[i][7] = wb.w;
    }
    float xf[8][4];
#pragma unroll
    for (int j = 0; j < 8; ++j) {
      const float4 xv =
          *(const float4*)&Xs[(rg * 8 + j) * 132 + ((d0 + 4 * rg) & 127)];
      xf[j][0] = xv.x; xf[j][1] = xv.y; xf[j][2] = xv.z; xf[j][3] = xv.w;
    }
#pragma unroll
    for (int i = 0; i < 4; ++i)
#pragma unroll
      for (int j = 0; j < 8; ++j)
#pragma unroll
        for (int c = 0; c < 8; ++c)
          acc[j][c] = fmaf(xf[j][i], w[i][c], acc[j][c]);
  }

  const float4 b0 = *(const float4*)(args.b[p] + c0);
  const float4 b1 = *(const float4*)(args.b[p] + c0 + 4);
  const float bias[8] = {b0.x, b0.y, b0.z, b0.w, b1.x, b1.y, b1.z, b1.w};
#pragma unroll
  for (int j = 0; j < 8; ++j) {
    float v[8];
#pragma unroll
    for (int c = 0; c < 8; ++c) {
      float a = acc[j][c] + bias[c];
      if (p == 1)      a *= 0.088388347648318447f;
      else if (p == 2) a = __expf(a);
      else if (p == 3 || p == 5) a = 1.0f / (1.0f + __expf(-a));
      v[c] = a;
    }
    float* dst = act + (size_t)p * BTH + (size_t)(row0 + rg * 8 + j) * HH + c0;
    *(float4*)dst = make_float4(v[0], v[1], v[2], v[3]);
    *(float4*)(dst + 4) = make_float4(v[4], v[5], v[6], v[7]);
  }
}

// ---------------------------------------------------------------------------
// sker: per (b,c,j): chunk summaries P31[j] = prod f, Sn[j] = sum i*k/P.
// Non-destructive. grid 128 ((b<<4)|c), block 128 (j).
// ---------------------------------------------------------------------------
__global__ __launch_bounds__(128)
void sker(const float* __restrict__ act, float* __restrict__ P31s,
          float* __restrict__ Sns) {
  const int b = blockIdx.x >> 4, c = blockIdx.x & 15;
  const int j = threadIdx.x;
  const float* kp = act + BTH;
  const float* ip = act + 2 * BTH;
  const float* fp = act + 3 * BTH;
  float P = 1.f, Sn = 0.f;
#pragma unroll 4
  for (int s = 0; s < CS; ++s) {
    const size_t base = ((size_t)b * TT + CS * c + s) * HH + j;
    const float fv = fp[base], iv = ip[base], kv = kp[base];
    P *= fv;
    Sn = fmaf(iv * kv, __builtin_amdgcn_rcpf(P), Sn);
  }
  P31s[(size_t)(b * NC + c) * HH + j] = P;
  Sns[(size_t)(b * NC + c) * HH + j] = Sn;
}

// ---------------------------------------------------------------------------
// n2ker: boundary n vectors, sequential over 16 chunks (tiny).
// grid 8 (b), block 128 (j). nbs[b][c][j] = n at chunk c start.
// ---------------------------------------------------------------------------
__global__ __launch_bounds__(128)
void n2ker(const float* __restrict__ P31s, const float* __restrict__ Sns,
           float* __restrict__ nbs) {
  const int b = blockIdx.x;
  const int j = threadIdx.x;
  float nb = 0.f;
#pragma unroll
  for (int c = 0; c < NC; ++c) {
    const size_t o = (size_t)(b * NC + c) * HH + j;
    nbs[o] = nb;
    nb = P31s[o] * (nb + Sns[o]);
  }
}

// ---------------------------------------------------------------------------
// dker: denominators. grid 128 ((b<<4)|c), one wave. Lane owns cols {2l,2l+1}.
// Exact 32-step intra-chunk n recurrence from nbs; invd[t] = 1/max(|n.q|,1).
// Runs BEFORE gker (needs original i,f planes).
// ---------------------------------------------------------------------------
__global__ __launch_bounds__(64)
void dker(const float* __restrict__ act, const float* __restrict__ nbs,
          float* __restrict__ invd) {
  const int b = blockIdx.x >> 4, c = blockIdx.x & 15;
  const int lane = threadIdx.x;
  const float* qp = act;
  const float* kp = act + BTH;
  const float* ip = act + 2 * BTH;
  const float* fp = act + 3 * BTH;
  const float2 nb2 = *(const float2*)(nbs + (size_t)(b * NC + c) * HH + 2 * lane);
  float n0 = nb2.x, n1 = nb2.y;
#pragma unroll 4
  for (int s = 0; s < CS; ++s) {
    const int t = CS * c + s;
    const size_t base = ((size_t)b * TT + t) * HH + 2 * lane;
    const float2 qv = *(const float2*)(qp + base);
    const float2 kv = *(const float2*)(kp + base);
    const float2 iv = *(const float2*)(ip + base);
    const float2 fv = *(const float2*)(fp + base);
    const float dp = red64(fmaf(n0, qv.x, n1 * qv.y));
    if (lane == 63) invd[b * TT + t] = 1.0f / fmaxf(fabsf(dp), 1.0f);
    n0 = fmaf(fv.x, n0, iv.x * kv.x);
    n1 = fmaf(fv.y, n1, iv.y * kv.y);
  }
}

// ---------------------------------------------------------------------------
// gker: per (b,c,i): cumprod P, write Pm1 over i-plane, G over v-plane.
// ---------------------------------------------------------------------------
__global__ __launch_bounds__(128)
void gker(float* __restrict__ act) {
  const int b = blockIdx.x >> 4, c = blockIdx.x & 15;
  const int i = threadIdx.x;
  float* iP = act + 2 * BTH;
  float* fP = act + 3 * BTH;
  float* vG = act + 4 * BTH;
  float P = 1.f;
#pragma unroll 1
  for (int s = 0; s < CS; ++s) {
    const size_t base = ((size_t)b * TT + CS * c + s) * HH + i;
    const float fv = fP[base], iv = iP[base], vv = vG[base];
    iP[base] = P;            // Pm1 (P_{s-1})
    P *= fv;
    vG[base] = iv * vv / P;  // G
  }
}

// ---------------------------------------------------------------------------
// aker: A[b][c][s][s'] = (s' < s) ? q_s . k_s' : 0.   grid 128, block 256.
// ---------------------------------------------------------------------------
#define PADQ 132
__global__ __launch_bounds__(256)
void aker(const float* __restrict__ act, float* __restrict__ Abuf) {
  __shared__ float Qc[CS * PADQ], Kc[CS * PADQ];
  const int b = blockIdx.x >> 4, c = blockIdx.x & 15;
  const int tid = threadIdx.x;
  const size_t cb = ((size_t)b * TT + CS * c) * HH;
  {
    const float4* qg = (const float4*)(act + cb);
    const float4* kg = (const float4*)(act + BTH + cb);
#pragma unroll
    for (int m = 0; m < 4; ++m) {
      const int v = tid + 256 * m;
      const int s = v >> 5, d0 = (v & 31) * 4;
      *(float4*)&Qc[s * PADQ + d0] = qg[v];
      *(float4*)&Kc[s * PADQ + d0] = kg[v];
    }
  }
  __syncthreads();
  const int s2 = tid >> 4, sp2 = tid & 15;
  float a00 = 0, a01 = 0, a10 = 0, a11 = 0;
#pragma unroll 2
  for (int dq = 0; dq < 32; ++dq) {
    const int d0 = dq * 4;
    const float4 qa = *(const float4*)&Qc[(2 * s2) * PADQ + d0];
    const float4 qb = *(const float4*)&Qc[(2 * s2 + 1) * PADQ + d0];
    const float4 ka = *(const float4*)&Kc[(2 * sp2) * PADQ + d0];
    const float4 kb = *(const float4*)&Kc[(2 * sp2 + 1) * PADQ + d0];
    a00 += qa.x*ka.x + qa.y*ka.y + qa.z*ka.z + qa.w*ka.w;
    a01 += qa.x*kb.x + qa.y*kb.y + qa.z*kb.z + qa.w*kb.w;
    a10 += qb.x*ka.x + qb.y*ka.y + qb.z*ka.z + qb.w*ka.w;
    a11 += qb.x*kb.x + qb.y*kb.y + qb.z*kb.z + qb.w*kb.w;
  }
  float* dst = Abuf + (size_t)(b * NC + c) * 1024;
  const int sa = 2 * s2, sb = 2 * s2 + 1, ta = 2 * sp2, tb = 2 * sp2 + 1;
  dst[sa * 32 + ta] = (ta < sa) ? a00 : 0.f;
  dst[sa * 32 + tb] = (tb < sa) ? a01 : 0.f;
  dst[sb * 32 + ta] = (ta < sb) ? a10 : 0.f;
  dst[sb * 32 + tb] = (tb < sb) ? a11 : 0.f;
}

// ---------------------------------------------------------------------------
// seqk: 16 sequential chunk iterations. grid 64 (b&7, col-slice>>3), block 256.
// ---------------------------------------------------------------------------
#define Q_OFF 0
#define K_OFF 4224
#define A_OFF 8448
#define G_OFF 9472
#define P_OFF 9984
#define O_OFF 10496
#define V_OFF 11008
#define F_OFF 11040
#define BUFS  11056
#define HST_OFF (2 * BUFS)

struct SR { float4 q[4], k[4], a, x1, x2, x3; };

__global__ __launch_bounds__(256, 1)
void seqk(const float* __restrict__ act, const float* __restrict__ Abuf,
          const float* __restrict__ invd, float* __restrict__ hout) {
  __shared__ float smem[2 * BUFS + CS * 16];
  const int tid = threadIdx.x;
  const int b = blockIdx.x & 7, sl = blockIdx.x >> 3;
  const int lane = tid & 63, w = tid >> 6;
  const float* qp = act;
  const float* kp = act + BTH;
  const float* Pm1p = act + 2 * BTH;
  const float* fp = act + 3 * BTH;
  const float* Gp = act + 4 * BTH;
  const float* op = act + 5 * BTH;

  float C[4][2];
#pragma unroll
  for (int j = 0; j < 4; ++j) { C[j][0] = 0.f; C[j][1] = 0.f; }

  auto stage_load = [&](int c, SR& sr) {
    const size_t cb = ((size_t)b * TT + CS * c) * HH;
    const float4* qg = (const float4*)(qp + cb);
    const float4* kg = (const float4*)(kp + cb);
#pragma unroll
    for (int m = 0; m < 4; ++m) {
      sr.q[m] = qg[tid + 256 * m];
      sr.k[m] = kg[tid + 256 * m];
    }
    sr.a = ((const float4*)(Abuf + (size_t)(b * NC + c) * 1024))[tid];
    const int t1 = tid & 127;
    const int s = t1 >> 2, j0 = (t1 & 3) * 4;
    const float* p1 = (tid < 128) ? Gp : Pm1p;
    sr.x1 = *(const float4*)(p1 + cb + (size_t)s * HH + sl * 16 + j0);
    sr.x2 = *(const float4*)(op + cb + (size_t)s * HH + sl * 16 + j0);
    if (tid < 8)
      sr.x3 = *(const float4*)(invd + b * TT + CS * c + tid * 4);
    else if (tid < 12)
      sr.x3 = *(const float4*)(fp + cb + (size_t)31 * HH + sl * 16 +
                               (tid - 8) * 4);
  };
  auto stage_store = [&](int d, const SR& sr) {
    float* B = smem + d * BUFS;
#pragma unroll
    for (int m = 0; m < 4; ++m) {
      const int v = tid + 256 * m;
      const int s = v >> 5, d0 = (v & 31) * 4;
      *(float4*)&B[Q_OFF + s * PADQ + d0] = sr.q[m];
      *(float4*)&B[K_OFF + s * PADQ + d0] = sr.k[m];
    }
    { const int s = tid >> 3, o = (tid & 7) * 4;
      *(float4*)&B[A_OFF + s * 32 + o] = sr.a; }
    { const int t1 = tid & 127;
      const int s = t1 >> 2, j0 = (t1 & 3) * 4;
      if (tid < 128) {
        *(float4*)&B[G_OFF + s * 16 + j0] = sr.x1;
        *(float4*)&B[O_OFF + s * 16 + j0] = sr.x2;
      } else {
        *(float4*)&B[P_OFF + s * 16 + j0] = sr.x1;
      } }
    if (tid < 8) *(float4*)&B[V_OFF + tid * 4] = sr.x3;
    else if (tid < 12) *(float4*)&B[F_OFF + (tid - 8) * 4] = sr.x3;
  };

  SR sr;
  stage_load(0, sr);
  stage_store(0, sr);
  __syncthreads();

#pragma unroll 1
  for (int c = 0; c < NC; ++c) {
    if (c + 1 < NC) stage_load(c + 1, sr);
    const float* B = smem + (c & 1) * BUFS;
    const float4 Greg = *(const float4*)&B[G_OFF + (lane & 31) * 16 + 4 * w];

    // ---- h pass ----
#pragma unroll 2
    for (int s = 0; s < CS; ++s) {
      const float2 qv = *(const float2*)&B[Q_OFF + s * PADQ + 2 * lane];
      float av = B[A_OFF + s * 32 + (lane & 31)];
      av = (lane < 32) ? av : 0.f;
      float r0 = fmaf(C[0][0], qv.x, fmaf(C[0][1], qv.y, av * Greg.x));
      float r1 = fmaf(C[1][0], qv.x, fmaf(C[1][1], qv.y, av * Greg.y));
      float r2 = fmaf(C[2][0], qv.x, fmaf(C[2][1], qv.y, av * Greg.z));
      float r3 = fmaf(C[3][0], qv.x, fmaf(C[3][1], qv.y, av * Greg.w));
      r0 = red64(r0); r1 = red64(r1); r2 = red64(r2); r3 = red64(r3);
      if (lane == 63)
        *(float4*)&smem[HST_OFF + s * 16 + 4 * w] = make_float4(r0, r1, r2, r3);
    }
    __syncthreads();

    // ---- state update ----
#pragma unroll 4
    for (int sp = 0; sp < CS; ++sp) {
      const float2 kv = *(const float2*)&B[K_OFF + sp * PADQ + 2 * lane];
      const float4 g4 = *(const float4*)&B[G_OFF + sp * 16 + 4 * w];
      C[0][0] = fmaf(g4.x, kv.x, C[0][0]); C[0][1] = fmaf(g4.x, kv.y, C[0][1]);
      C[1][0] = fmaf(g4.y, kv.x, C[1][0]); C[1][1] = fmaf(g4.y, kv.y, C[1][1]);
      C[2][0] = fmaf(g4.z, kv.x, C[2][0]); C[2][1] = fmaf(g4.z, kv.y, C[2][1]);
      C[3][0] = fmaf(g4.w, kv.x, C[3][0]); C[3][1] = fmaf(g4.w, kv.y, C[3][1]);
    }
    { const float4 pm = *(const float4*)&B[P_OFF + 31 * 16 + 4 * w];
      const float4 f31 = *(const float4*)&B[F_OFF + 4 * w];
      const float p31[4] = {pm.x * f31.x, pm.y * f31.y, pm.z * f31.z,
                            pm.w * f31.w};
#pragma unroll
      for (int j = 0; j < 4; ++j) { C[j][0] *= p31[j]; C[j][1] *= p31[j]; } }

    // ---- epilogue ----
#pragma unroll
    for (int e = 0; e < 2; ++e) {
      const int v = tid + 256 * e;
      const int s = v >> 4, j = v & 15;
      const float hv =
          smem[HST_OFF + v] * B[P_OFF + v] * B[O_OFF + v] * B[V_OFF + s];
      hout[((size_t)b * TT + CS * c + s) * HH + sl * 16 + j] = hv;
    }

    if (c + 1 < NC) stage_store((c + 1) & 1, sr);
    __syncthreads();
  }
}

// ---------------------------------------------------------------------------
extern "C" void kernel_launch(void* const* d_in, const int* in_sizes, int n_in,
                              void* d_out, int out_size, void* d_ws,
                              size_t ws_size, hipStream_t stream) {
  (void)in_sizes; (void)n_in; (void)out_size; (void)ws_size;
  const float* x = (const float*)d_in[0];
  float* act = (float*)d_ws;
  float* hbuf = act + 6 * BTH;
  float* Abuf = act + 7 * BTH;
  float* invd = Abuf + (size_t)BB * NC * 1024;   // 131072
  float* P31s = invd + BB * TT;                  // 4096
  float* Sns  = P31s + BB * NC * HH;             // 16384
  float* nbs  = Sns + BB * NC * HH;              // 16384
  float* Wt = (float*)d_out;  // 196608 floats, consumed before final seqk

  const int wi[6] = {1, 2, 4, 5, 3, 6};
  const int bi[6] = {7, 8, 10, 11, 9, 12};
  WArgs wa;
  for (int j = 0; j < 6; ++j) wa.W[j] = (const float*)d_in[wi[j]];
  transpose_w<<<dim3(16, 12), 256, 0, stream>>>(wa, Wt);

  for (int l = 0; l < 2; ++l) {
    BArgs ba;
    for (int j = 0; j < 6; ++j)
      ba.b[j] = (const float*)d_in[bi[j]] + (size_t)l * HH;
    const float* wtl = Wt + (size_t)l * 6 * HH * DD;
    const float* xin = (l == 0) ? x : hbuf;
    float* hdst = (l == 0) ? hbuf : (float*)d_out;
    proj_kernel<<<dim3(32, 6), 256, 0, stream>>>(xin, wtl, ba, act);
    sker<<<128, 128, 0, stream>>>(act, P31s, Sns);
    n2ker<<<8, 128, 0, stream>>>(P31s, Sns, nbs);
    dker<<<128, 64, 0, stream>>>(act, nbs, invd);
    gker<<<128, 128, 0, stream>>>(act);
    aker<<<128, 256, 0, stream>>>(act, Abuf);
    seqk<<<64, 256, 0, stream>>>(act, Abuf, invd, hdst);
  }
}